// Round 4
// baseline (4757.475 us; speedup 1.0000x reference)
//
#include <hip/hip_runtime.h>
#include <hip/hip_bf16.h>

typedef __bf16 bf16;
typedef __bf16 bf16x8 __attribute__((ext_vector_type(8)));
typedef float  f32x4  __attribute__((ext_vector_type(4)));

#define TT    128
#define BB    1024
#define VOCAB 128
#define EE    256
#define HH    1024
#define NTAGS 8
#define PW    1032            // LDS pitch for W_hh slice (bf16): 516 dw = 4 mod 32 banks
#define LDS_SW_B   (64 * PW * 2)            // 132096
#define LDS_ST_OFF LDS_SW_B                 // h tile 64x72 bf16 = 9216
#define LDS_WO_OFF (LDS_ST_OFF + 64 * 72 * 2)   // 141312: W_out 8x64 f32 = 2048
#define LDS_ID_OFF (LDS_WO_OFF + 2048)          // 143360: ids 64 int
#define LDS_SL_OFF (LDS_ID_OFF + 256)           // 143616: seqlen 64 int
#define LDS_TOTAL  (LDS_SL_OFF + 256)           // 143872 B  (<160 KiB, 1 block/CU)

// ---------------------------------------------------------------- fp32 -> bf16
__global__ __launch_bounds__(256) void cvt_k(const float* __restrict__ s,
                                             bf16* __restrict__ d, int n) {
    int i = (blockIdx.x * 256 + threadIdx.x) * 4;
    if (i >= n) return;
    float4 v = *(const float4*)(s + i);
    bf16 o0 = (bf16)v.x, o1 = (bf16)v.y, o2 = (bf16)v.z, o3 = (bf16)v.w;
    bf16 o[4] = {o0, o1, o2, o3};
    *(short4*)(d + i) = *(short4*)o;
}

// ---------------------------------------------------------------- seq lengths
__global__ __launch_bounds__(256) void seqlen_k(const int* __restrict__ ids,
                                                int* __restrict__ sl) {
    int b = blockIdx.x * 256 + threadIdx.x;
    int c = 0;
    for (int t = 0; t < TT; ++t) c += (ids[b * TT + t] != 0) ? 1 : 0;
    sl[b] = c;
}

// ---------------------------------------------------------------- XP precompute
// XP[v][n] = emb[v,:] . W_ih[n,:] + b_ih[n] + b_hh[n]   (fp32, 128x1024)
__global__ __launch_bounds__(256) void xp_k(const float* __restrict__ emb,
                                            const float* __restrict__ W_ih,
                                            const float* __restrict__ b_ih,
                                            const float* __restrict__ b_hh,
                                            float* __restrict__ XP) {
    __shared__ float se[EE];
    const int v = blockIdx.x;               // 128 blocks
    se[threadIdx.x] = emb[v * EE + threadIdx.x];
    __syncthreads();
    const int c0 = threadIdx.x * 4;         // 4 output cols per thread
    float s0 = 0.f, s1 = 0.f, s2 = 0.f, s3 = 0.f;
    for (int e = 0; e < EE; e += 4) {
        float4 ev = *(const float4*)(se + e);
        float4 w0 = *(const float4*)(W_ih + (c0 + 0) * EE + e);
        float4 w1 = *(const float4*)(W_ih + (c0 + 1) * EE + e);
        float4 w2 = *(const float4*)(W_ih + (c0 + 2) * EE + e);
        float4 w3 = *(const float4*)(W_ih + (c0 + 3) * EE + e);
        s0 += ev.x * w0.x + ev.y * w0.y + ev.z * w0.z + ev.w * w0.w;
        s1 += ev.x * w1.x + ev.y * w1.y + ev.z * w1.z + ev.w * w1.w;
        s2 += ev.x * w2.x + ev.y * w2.y + ev.z * w2.z + ev.w * w2.w;
        s3 += ev.x * w3.x + ev.y * w3.y + ev.z * w3.z + ev.w * w3.w;
    }
    XP[v * HH + c0 + 0] = s0 + b_ih[c0 + 0] + b_hh[c0 + 0];
    XP[v * HH + c0 + 1] = s1 + b_ih[c0 + 1] + b_hh[c0 + 1];
    XP[v * HH + c0 + 2] = s2 + b_ih[c0 + 2] + b_hh[c0 + 2];
    XP[v * HH + c0 + 3] = s3 + b_ih[c0 + 3] + b_hh[c0 + 3];
}

// ---------------------------------------------------------------- persistent RNN
// 256 blocks (16 M-groups x 16 N-slices of 64), 256 threads (4 waves, 32x32 each).
// W_hh slice LDS-resident across all 128 steps; h exchanged via global double
// buffer with per-M-group atomic barriers (cooperative launch for residency).
__global__ __launch_bounds__(256)
void rnn_persist(const int*   __restrict__ ids,
                 const float* __restrict__ XP,
                 const bf16*  __restrict__ Whh,
                 const float* __restrict__ W_out,
                 const int*   __restrict__ sl,
                 bf16* h0, bf16* h1,
                 float* __restrict__ y_acc,
                 unsigned* __restrict__ bar)
{
    extern __shared__ __align__(16) char smem[];
    bf16*  sW   = (bf16*)smem;                       // [64][PW]
    bf16*  sT   = (bf16*)(smem + LDS_ST_OFF);        // [64][72] post-mask h tile
    float* sWo  = (float*)(smem + LDS_WO_OFF);       // [8][64]
    int*   sIds = (int*)(smem + LDS_ID_OFF);         // [64]
    int*   sSl  = (int*)(smem + LDS_SL_OFF);         // [64]

    const int tid = threadIdx.x;
    const int bid = blockIdx.x;
    const int gn = bid & 15, gm = bid >> 4;
    const int Nbase = gn * 64, Mbase = gm * 64;

    // one-time staging
    for (int i = tid; i < 64 * 128; i += 256) {      // W_hh slice, 8192 x int4
        int r = i >> 7, c = (i & 127) * 8;
        *(int4*)(sW + r * PW + c) = *(const int4*)(Whh + (Nbase + r) * HH + c);
    }
    if (tid < 128) {                                 // W_out slice (8 tags x 64)
        int tg = tid >> 4, c = (tid & 15) * 4;
        *(float4*)(sWo + tg * 64 + c) = *(const float4*)(W_out + tg * HH + Nbase + c);
    }
    if (tid < 64) sSl[tid] = sl[Mbase + tid];
    __syncthreads();

    const int wave = tid >> 6, lane = tid & 63;
    const int quad = lane >> 4, l15 = lane & 15;
    const int wm = (wave >> 1) * 32, wn = (wave & 1) * 32;

    unsigned tgt = 0;
    for (int s = 0; s < TT; ++s) {
        const bf16* hp = (s & 1) ? h1 : h0;
        bf16*       hn = (s & 1) ? h0 : h1;

        f32x4 acc[2][2];
#pragma unroll
        for (int a = 0; a < 2; ++a)
#pragma unroll
            for (int b = 0; b < 2; ++b) {
                f32x4 z = {0.f, 0.f, 0.f, 0.f};
                acc[a][b] = z;
            }

        const bf16* aR0 = hp + (size_t)(Mbase + wm + l15) * HH;
        const bf16* aR1 = hp + (size_t)(Mbase + wm + 16 + l15) * HH;
        const bf16* bR0 = sW + (wn + l15) * PW;
        const bf16* bR1 = sW + (wn + 16 + l15) * PW;
#pragma unroll 4
        for (int kk = 0; kk < HH; kk += 32) {
            const int ko = kk + quad * 8;
            bf16x8 a0 = *(const bf16x8*)(aR0 + ko);
            bf16x8 a1 = *(const bf16x8*)(aR1 + ko);
            bf16x8 b0 = *(const bf16x8*)(bR0 + ko);
            bf16x8 b1 = *(const bf16x8*)(bR1 + ko);
            acc[0][0] = __builtin_amdgcn_mfma_f32_16x16x32_bf16(a0, b0, acc[0][0], 0, 0, 0);
            acc[0][1] = __builtin_amdgcn_mfma_f32_16x16x32_bf16(a0, b1, acc[0][1], 0, 0, 0);
            acc[1][0] = __builtin_amdgcn_mfma_f32_16x16x32_bf16(a1, b0, acc[1][0], 0, 0, 0);
            acc[1][1] = __builtin_amdgcn_mfma_f32_16x16x32_bf16(a1, b1, acc[1][1], 0, 0, 0);
        }

        if (tid < 64) sIds[tid] = ids[(Mbase + tid) * TT + s];
        __syncthreads();

        // epilogue: XP lookup + tanh + mask -> post-mask h into sT
#pragma unroll
        for (int sm = 0; sm < 2; ++sm)
#pragma unroll
            for (int sn = 0; sn < 2; ++sn)
#pragma unroll
                for (int r = 0; r < 4; ++r) {
                    int row = wm + sm * 16 + quad * 4 + r;     // batch-local
                    int col = wn + sn * 16 + l15;              // N-local
                    float pre = acc[sm][sn][r] +
                                XP[(size_t)sIds[row] * HH + Nbase + col];
                    float nh = tanhf(pre);
                    bf16 hv;
                    if (s < sSl[row]) hv = (bf16)nh;
                    else hv = hp[(size_t)(Mbase + row) * HH + Nbase + col];
                    sT[row * 72 + col] = hv;
                }
        __syncthreads();

        // h store (vectorized from sT) + per-slice logit partials
        {
            const int row = tid >> 2, q = tid & 3;
            bf16* dst = hn + (size_t)(Mbase + row) * HH + Nbase + q * 16;
            const bf16* srcp = sT + row * 72 + q * 16;
            *(int4*)(dst)     = *(const int4*)(srcp);
            *(int4*)(dst + 8) = *(const int4*)(srcp + 8);

            bf16x8 hv0 = *(const bf16x8*)(srcp);
            bf16x8 hv1 = *(const bf16x8*)(srcp + 8);
            float* ybase = y_acc + (size_t)(Mbase + row) * (TT * NTAGS) + s * NTAGS;
#pragma unroll
            for (int tg = 0; tg < NTAGS; ++tg) {
                const float* w = sWo + tg * 64 + q * 16;
                float p = 0.f;
#pragma unroll
                for (int j = 0; j < 8; ++j) p += (float)hv0[j] * w[j];
#pragma unroll
                for (int j = 0; j < 8; ++j) p += (float)hv1[j] * w[8 + j];
                p += __shfl_xor(p, 1);
                p += __shfl_xor(p, 2);
                if (q == 0) atomicAdd(ybase + tg, p);
            }
        }

        // group barrier: release h stores, arrive, spin, acquire
        __syncthreads();                 // drains vmcnt for all waves
        tgt += 16;
        if (tid == 0) {
            __threadfence();             // L2 writeback: h visible device-wide
            __hip_atomic_fetch_add(&bar[gm], 1u, __ATOMIC_RELEASE,
                                   __HIP_MEMORY_SCOPE_AGENT);
            while (__hip_atomic_load(&bar[gm], __ATOMIC_ACQUIRE,
                                     __HIP_MEMORY_SCOPE_AGENT) < tgt)
                __builtin_amdgcn_s_sleep(2);
        }
        __syncthreads();
    }
}

// ---------------------------------------------------------------- bias add
__global__ __launch_bounds__(256) void bias_k(const float* __restrict__ y,
                                              const float* __restrict__ b_out,
                                              float* __restrict__ out) {
    int i4 = (blockIdx.x * 256 + threadIdx.x) * 4;   // 1024 blocks -> 1,048,576
    float4 v = *(const float4*)(y + i4);
    int b = i4 & 7;                                   // 0 or 4
    v.x += b_out[b + 0]; v.y += b_out[b + 1];
    v.z += b_out[b + 2]; v.w += b_out[b + 3];
    *(float4*)(out + i4) = v;
}

// ---------------------------------------------------------------- launch
extern "C" void kernel_launch(void* const* d_in, const int* in_sizes, int n_in,
                              void* d_out, int out_size, void* d_ws, size_t ws_size,
                              hipStream_t stream) {
    const int*   ids   = (const int*)d_in[0];
    const float* emb   = (const float*)d_in[1];
    const float* W_ih  = (const float*)d_in[2];
    const float* W_hh  = (const float*)d_in[3];
    const float* b_ih  = (const float*)d_in[4];
    const float* b_hh  = (const float*)d_in[5];
    const float* W_out = (const float*)d_in[6];
    const float* b_out = (const float*)d_in[7];
    float* out = (float*)d_out;

    // ws: sl | XP | Whh16 | h0 | h1 | y_acc | bar   (~10.6 MB)
    char* ws = (char*)d_ws;
    size_t off = 0;
    int*      sl    = (int*)(ws + off);      off += 4096;
    float*    XP    = (float*)(ws + off);    off += (size_t)VOCAB * HH * 4;   // 512 KB
    bf16*     Whh16 = (bf16*)(ws + off);     off += (size_t)HH * HH * 2;      // 2 MB
    bf16*     h0    = (bf16*)(ws + off);     off += (size_t)BB * HH * 2;      // 2 MB
    bf16*     h1    = (bf16*)(ws + off);     off += (size_t)BB * HH * 2;      // 2 MB
    float*    y_acc = (float*)(ws + off);    off += (size_t)BB * TT * NTAGS * 4; // 4 MB
    unsigned* bar   = (unsigned*)(ws + off); off += 128;
    if (ws_size < off) return;

    hipMemsetAsync(bar, 0, 128, stream);
    hipMemsetAsync(h0, 0, (size_t)BB * HH * 2, stream);
    hipMemsetAsync(y_acc, 0, (size_t)BB * TT * NTAGS * 4, stream);

    cvt_k<<<(HH * HH / 4 + 255) / 256, 256, 0, stream>>>(W_hh, Whh16, HH * HH);
    xp_k<<<VOCAB, 256, 0, stream>>>(emb, W_ih, b_ih, b_hh, XP);
    seqlen_k<<<4, 256, 0, stream>>>(ids, sl);

    hipFuncSetAttribute((const void*)rnn_persist,
                        hipFuncAttributeMaxDynamicSharedMemorySize, LDS_TOTAL);

    {
        const int*   a0 = ids;  const float* a1 = XP;  const bf16* a2 = Whh16;
        const float* a3 = W_out; const int*  a4 = sl;
        bf16* a5 = h0; bf16* a6 = h1; float* a7 = y_acc; unsigned* a8 = bar;
        void* args[] = {&a0, &a1, &a2, &a3, &a4, &a5, &a6, &a7, &a8};
        hipLaunchCooperativeKernel((const void*)rnn_persist, dim3(256), dim3(256),
                                   args, LDS_TOTAL, stream);
    }

    bias_k<<<BB * TT * NTAGS / 1024, 256, 0, stream>>>(y_acc, b_out, out);
}

// Round 5
// 2781.281 us; speedup vs baseline: 1.7105x; 1.7105x over previous
//
#include <hip/hip_runtime.h>
#include <hip/hip_bf16.h>

typedef __bf16 bf16;
typedef __bf16 bf16x8 __attribute__((ext_vector_type(8)));
typedef float  f32x4  __attribute__((ext_vector_type(4)));

#define TT    128
#define BB    1024
#define VOCAB 128
#define EE    256
#define HH    1024
#define NTAGS 8

#define BM 64
#define BN 64
#define BK 128
#define PT 136                 // LDS row pitch (bf16): 272B rows, 16B-aligned, 2-way banks (free)
#define NKT (HH / BK)          // 8 K-tiles per step

// dynamic LDS layout
#define OFF_SA 0                                   // 2 bufs x 64 x PT bf16 = 34816
#define OFF_SB (OFF_SA + 2 * BM * PT * 2)          // 34816 -> + 34816 = 69632
#define OFF_ST (OFF_SB + 2 * BN * PT * 2)          // h tile 64x72 bf16 = 9216
#define OFF_WO (OFF_ST + BM * 72 * 2)              // 8x64 f32 = 2048
#define OFF_ID (OFF_WO + NTAGS * 64 * 4)           // 64 int
#define OFF_SL (OFF_ID + 256)                      // 64 int
#define LDS_TOTAL (OFF_SL + 256)                   // 81408 B

// ---------------------------------------------------------------- fp32 -> bf16
__global__ __launch_bounds__(256) void cvt_k(const float* __restrict__ s,
                                             bf16* __restrict__ d, int n) {
    int i = (blockIdx.x * 256 + threadIdx.x) * 4;
    if (i >= n) return;
    float4 v = *(const float4*)(s + i);
    bf16 o[4] = {(bf16)v.x, (bf16)v.y, (bf16)v.z, (bf16)v.w};
    *(short4*)(d + i) = *(short4*)o;
}

// ---------------------------------------------------------------- seq lengths
__global__ __launch_bounds__(256) void seqlen_k(const int* __restrict__ ids,
                                                int* __restrict__ sl) {
    int b = blockIdx.x * 256 + threadIdx.x;
    int c = 0;
    for (int t = 0; t < TT; ++t) c += (ids[b * TT + t] != 0) ? 1 : 0;
    sl[b] = c;
}

// ---------------------------------------------------------------- XP precompute
// XP[v][n] = emb[v,:] . W_ih[n,:] + b_ih[n] + b_hh[n]   (fp32, 128x1024)
__global__ __launch_bounds__(256) void xp_k(const float* __restrict__ emb,
                                            const float* __restrict__ W_ih,
                                            const float* __restrict__ b_ih,
                                            const float* __restrict__ b_hh,
                                            float* __restrict__ XP) {
    __shared__ float se[EE];
    const int v = blockIdx.x;
    se[threadIdx.x] = emb[v * EE + threadIdx.x];
    __syncthreads();
    const int c0 = threadIdx.x * 4;
    float s0 = 0.f, s1 = 0.f, s2 = 0.f, s3 = 0.f;
    for (int e = 0; e < EE; e += 4) {
        float4 ev = *(const float4*)(se + e);
        float4 w0 = *(const float4*)(W_ih + (c0 + 0) * EE + e);
        float4 w1 = *(const float4*)(W_ih + (c0 + 1) * EE + e);
        float4 w2 = *(const float4*)(W_ih + (c0 + 2) * EE + e);
        float4 w3 = *(const float4*)(W_ih + (c0 + 3) * EE + e);
        s0 += ev.x * w0.x + ev.y * w0.y + ev.z * w0.z + ev.w * w0.w;
        s1 += ev.x * w1.x + ev.y * w1.y + ev.z * w1.z + ev.w * w1.w;
        s2 += ev.x * w2.x + ev.y * w2.y + ev.z * w2.z + ev.w * w2.w;
        s3 += ev.x * w3.x + ev.y * w3.y + ev.z * w3.z + ev.w * w3.w;
    }
    XP[v * HH + c0 + 0] = s0 + b_ih[c0 + 0] + b_hh[c0 + 0];
    XP[v * HH + c0 + 1] = s1 + b_ih[c0 + 1] + b_hh[c0 + 1];
    XP[v * HH + c0 + 2] = s2 + b_ih[c0 + 2] + b_hh[c0 + 2];
    XP[v * HH + c0 + 3] = s3 + b_ih[c0 + 3] + b_hh[c0 + 3];
}

// ---------------------------------------------------------------- one RNN step
// 256 blocks = 16 M x 16 N tiles of 64x64. 4 waves, each 32x32 (2x2 MFMA frags).
// K=1024 in 8 tiles of 128, double-buffered LDS + register prefetch:
// tile k+1's global loads are in flight across tile k's whole MFMA section.
__global__ __launch_bounds__(256)
void step_k(const int*   __restrict__ ids,
            const float* __restrict__ XP,
            const bf16*  __restrict__ Whh,
            const float* __restrict__ W_out,
            const int*   __restrict__ sl,
            const bf16*  __restrict__ hp,
            bf16*        __restrict__ hn,
            float*       __restrict__ y_acc,
            int s)
{
    extern __shared__ __align__(16) char smem[];
    bf16*  sA   = (bf16*)(smem + OFF_SA);   // [2][64][PT]
    bf16*  sB   = (bf16*)(smem + OFF_SB);   // [2][64][PT]
    bf16*  sT   = (bf16*)(smem + OFF_ST);   // [64][72]
    float* sWo  = (float*)(smem + OFF_WO);  // [8][64]
    int*   sIds = (int*)(smem + OFF_ID);
    int*   sSl  = (int*)(smem + OFF_SL);

    const int tid = threadIdx.x;
    const int gm = blockIdx.x & 15, gn = blockIdx.x >> 4;
    const int Mbase = gm * 64, Nbase = gn * 64;
    const int wave = tid >> 6, lane = tid & 63;
    const int quad = lane >> 4, l15 = lane & 15;
    const int wm = (wave >> 1) * 32, wn = (wave & 1) * 32;
    const int r = tid >> 2, q = tid & 3;          // staging: row, col-quarter

    if (tid < 128) {
        int tg = tid >> 4, c = (tid & 15) * 4;
        *(float4*)(sWo + tg * 64 + c) = *(const float4*)(W_out + tg * HH + Nbase + c);
    }
    if (tid < 64) {
        sIds[tid] = ids[(Mbase + tid) * TT + s];
        sSl[tid]  = sl[Mbase + tid];
    }

    // prologue: tile 0 -> regs -> buf0
    const bf16* gA = hp  + (size_t)(Mbase + r) * HH + q * 32;
    const bf16* gB = Whh + (size_t)(Nbase + r) * HH + q * 32;
    int4 pa[4], pb[4];
#pragma unroll
    for (int j = 0; j < 4; ++j) {
        pa[j] = *(const int4*)(gA + j * 8);
        pb[j] = *(const int4*)(gB + j * 8);
    }
    {
        bf16* dA = sA + r * PT + q * 32;
        bf16* dB = sB + r * PT + q * 32;
#pragma unroll
        for (int j = 0; j < 4; ++j) {
            *(int4*)(dA + j * 8) = pa[j];
            *(int4*)(dB + j * 8) = pb[j];
        }
    }
    __syncthreads();

    f32x4 acc[2][2];
#pragma unroll
    for (int a = 0; a < 2; ++a)
#pragma unroll
        for (int b = 0; b < 2; ++b) {
            f32x4 z = {0.f, 0.f, 0.f, 0.f};
            acc[a][b] = z;
        }

    for (int kt = 0; kt < NKT; ++kt) {
        // issue next tile's global loads (latency hidden by this tile's MFMA)
        if (kt < NKT - 1) {
            const int kb = (kt + 1) * BK;
#pragma unroll
            for (int j = 0; j < 4; ++j) {
                pa[j] = *(const int4*)(gA + kb + j * 8);
                pb[j] = *(const int4*)(gB + kb + j * 8);
            }
        }
        const bf16* bufA = sA + (kt & 1) * (BM * PT);
        const bf16* bufB = sB + (kt & 1) * (BN * PT);
#pragma unroll
        for (int kk = 0; kk < BK; kk += 32) {
            const int ko = kk + quad * 8;
            bf16x8 a0 = *(const bf16x8*)(bufA + (wm + l15) * PT + ko);
            bf16x8 a1 = *(const bf16x8*)(bufA + (wm + 16 + l15) * PT + ko);
            bf16x8 b0 = *(const bf16x8*)(bufB + (wn + l15) * PT + ko);
            bf16x8 b1 = *(const bf16x8*)(bufB + (wn + 16 + l15) * PT + ko);
            acc[0][0] = __builtin_amdgcn_mfma_f32_16x16x32_bf16(a0, b0, acc[0][0], 0, 0, 0);
            acc[0][1] = __builtin_amdgcn_mfma_f32_16x16x32_bf16(a0, b1, acc[0][1], 0, 0, 0);
            acc[1][0] = __builtin_amdgcn_mfma_f32_16x16x32_bf16(a1, b0, acc[1][0], 0, 0, 0);
            acc[1][1] = __builtin_amdgcn_mfma_f32_16x16x32_bf16(a1, b1, acc[1][1], 0, 0, 0);
        }
        // store prefetched regs into the other buffer (readers of it finished last iter)
        if (kt < NKT - 1) {
            bf16* nA = sA + ((kt + 1) & 1) * (BM * PT) + r * PT + q * 32;
            bf16* nB = sB + ((kt + 1) & 1) * (BN * PT) + r * PT + q * 32;
#pragma unroll
            for (int j = 0; j < 4; ++j) {
                *(int4*)(nA + j * 8) = pa[j];
                *(int4*)(nB + j * 8) = pb[j];
            }
        }
        __syncthreads();
    }

    // epilogue: XP lookup + tanh + mask -> sT
#pragma unroll
    for (int sm = 0; sm < 2; ++sm)
#pragma unroll
        for (int sn = 0; sn < 2; ++sn)
#pragma unroll
            for (int rr = 0; rr < 4; ++rr) {
                int row = wm + sm * 16 + quad * 4 + rr;
                int col = wn + sn * 16 + l15;
                float pre = acc[sm][sn][rr] +
                            XP[(size_t)sIds[row] * HH + Nbase + col];
                float nh = tanhf(pre);
                bf16 hv;
                if (s < sSl[row]) hv = (bf16)nh;
                else hv = hp[(size_t)(Mbase + row) * HH + Nbase + col];
                sT[row * 72 + col] = hv;
            }
    __syncthreads();

    // h store (vectorized) + folded per-step logits
    {
        const int row = tid >> 2, qq = tid & 3;
        bf16* dst = hn + (size_t)(Mbase + row) * HH + Nbase + qq * 16;
        const bf16* srcp = sT + row * 72 + qq * 16;
        *(int4*)(dst)     = *(const int4*)(srcp);
        *(int4*)(dst + 8) = *(const int4*)(srcp + 8);

        bf16x8 hv0 = *(const bf16x8*)(srcp);
        bf16x8 hv1 = *(const bf16x8*)(srcp + 8);
        float* yb = y_acc + (size_t)(Mbase + row) * (TT * NTAGS) + s * NTAGS;
#pragma unroll
        for (int tg = 0; tg < NTAGS; ++tg) {
            const float* w = sWo + tg * 64 + qq * 16;
            float p = 0.f;
#pragma unroll
            for (int j = 0; j < 8; ++j) p += (float)hv0[j] * w[j];
#pragma unroll
            for (int j = 0; j < 8; ++j) p += (float)hv1[j] * w[8 + j];
            p += __shfl_xor(p, 1);
            p += __shfl_xor(p, 2);
            if (qq == 0) atomicAdd(yb + tg, p);
        }
    }
}

// ---------------------------------------------------------------- bias add
__global__ __launch_bounds__(256) void bias_k(const float* __restrict__ y,
                                              const float* __restrict__ b_out,
                                              float* __restrict__ out) {
    int i4 = (blockIdx.x * 256 + threadIdx.x) * 4;
    float4 v = *(const float4*)(y + i4);
    int b = i4 & 7;
    v.x += b_out[b + 0]; v.y += b_out[b + 1];
    v.z += b_out[b + 2]; v.w += b_out[b + 3];
    *(float4*)(out + i4) = v;
}

// ---------------------------------------------------------------- launch
extern "C" void kernel_launch(void* const* d_in, const int* in_sizes, int n_in,
                              void* d_out, int out_size, void* d_ws, size_t ws_size,
                              hipStream_t stream) {
    const int*   ids   = (const int*)d_in[0];
    const float* emb   = (const float*)d_in[1];
    const float* W_ih  = (const float*)d_in[2];
    const float* W_hh  = (const float*)d_in[3];
    const float* b_ih  = (const float*)d_in[4];
    const float* b_hh  = (const float*)d_in[5];
    const float* W_out = (const float*)d_in[6];
    const float* b_out = (const float*)d_in[7];
    float* out = (float*)d_out;

    // ws: sl | XP | Whh16 | h0 | h1 | y_acc   (~10.5 MB)
    char* ws = (char*)d_ws;
    size_t off = 0;
    int*   sl    = (int*)(ws + off);   off += 4096;
    float* XP    = (float*)(ws + off); off += (size_t)VOCAB * HH * 4;       // 512 KB
    bf16*  Whh16 = (bf16*)(ws + off);  off += (size_t)HH * HH * 2;          // 2 MB
    bf16*  h0    = (bf16*)(ws + off);  off += (size_t)BB * HH * 2;          // 2 MB
    bf16*  h1    = (bf16*)(ws + off);  off += (size_t)BB * HH * 2;          // 2 MB
    float* y_acc = (float*)(ws + off); off += (size_t)BB * TT * NTAGS * 4;  // 4 MB
    if (ws_size < off) return;

    hipMemsetAsync(h0, 0, (size_t)BB * HH * 2, stream);
    hipMemsetAsync(y_acc, 0, (size_t)BB * TT * NTAGS * 4, stream);

    cvt_k<<<(HH * HH / 4 + 255) / 256, 256, 0, stream>>>(W_hh, Whh16, HH * HH);
    xp_k<<<VOCAB, 256, 0, stream>>>(emb, W_ih, b_ih, b_hh, XP);
    seqlen_k<<<4, 256, 0, stream>>>(ids, sl);

    hipFuncSetAttribute((const void*)step_k,
                        hipFuncAttributeMaxDynamicSharedMemorySize, LDS_TOTAL);

    bf16* hb[2] = {h0, h1};
    for (int t = 0; t < TT; ++t)
        step_k<<<256, 256, LDS_TOTAL, stream>>>(
            ids, XP, Whh16, W_out, sl, hb[t & 1], hb[(t + 1) & 1], y_acc, t);

    bias_k<<<BB * TT * NTAGS / 1024, 256, 0, stream>>>(y_acc, b_out, out);
}